// Round 6
// baseline (358.348 us; speedup 1.0000x reference)
//
#include <hip/hip_runtime.h>
#include <hip/hip_bf16.h>
#include <stdint.h>
#include <stddef.h>

typedef __attribute__((ext_vector_type(8))) short short8;
typedef __attribute__((ext_vector_type(4))) float f32x4;
typedef __attribute__((ext_vector_type(8))) unsigned short ushort8;

// global -> LDS direct copy, 16B per lane. LDS dest must be base + lane*16.
__device__ __forceinline__ void gload16(const void* g, void* l) {
    __builtin_amdgcn_global_load_lds(
        (__attribute__((address_space(1))) void*)g,
        (__attribute__((address_space(3))) void*)l,
        16, 0, 0);
}

// ---------------------------------------------------------------------------
__global__ void absmean_partial_k(const float* __restrict__ w,
                                  double* __restrict__ partials) {
    int tid = threadIdx.x;
    size_t base = (size_t)blockIdx.x * 8192 + (size_t)tid * 4;
    float s = 0.f;
#pragma unroll
    for (int i = 0; i < 8; ++i) {
        f32x4 v = *reinterpret_cast<const f32x4*>(w + base + (size_t)i * 1024);
        s += __builtin_fabsf(v.x) + __builtin_fabsf(v.y) +
             __builtin_fabsf(v.z) + __builtin_fabsf(v.w);
    }
    double d = (double)s;
#pragma unroll
    for (int off = 32; off > 0; off >>= 1) d += __shfl_down(d, off, 64);
    __shared__ double red[4];
    int lane = tid & 63, wid = tid >> 6;
    if (lane == 0) red[wid] = d;
    __syncthreads();
    if (tid == 0) partials[blockIdx.x] = red[0] + red[1] + red[2] + red[3];
}

__global__ void absmean_final_k(const double* __restrict__ partials,
                                float* __restrict__ sc, int nparts, int count) {
    int tid = threadIdx.x;
    double d = 0.0;
    for (int i = tid; i < nparts; i += 256) d += partials[i];
#pragma unroll
    for (int off = 32; off > 0; off >>= 1) d += __shfl_down(d, off, 64);
    __shared__ double red[4];
    int lane = tid & 63, wid = tid >> 6;
    if (lane == 0) red[wid] = d;
    __syncthreads();
    if (tid == 0) {
        double total = red[0] + red[1] + red[2] + red[3];
        float scale = (float)(total / (double)count);
        sc[0] = scale;
        sc[1] = scale + 1e-8f;
    }
}

__global__ void quantize_w_k(const float* __restrict__ w,
                             __hip_bfloat16* __restrict__ wq,
                             const float* __restrict__ sc) {
    float speps = sc[1];
    size_t i = ((size_t)blockIdx.x * 256 + threadIdx.x) * 8;
    f32x4 a = *reinterpret_cast<const f32x4*>(w + i);
    f32x4 b = *reinterpret_cast<const f32x4*>(w + i + 4);
    float v[8] = {a.x, a.y, a.z, a.w, b.x, b.y, b.z, b.w};
    ushort8 o;
#pragma unroll
    for (int j = 0; j < 8; ++j) {
        float t = v[j] / speps;
        t = fminf(fmaxf(t, -1.f), 1.f);
        float r = rintf(t);
        __hip_bfloat16 h = __float2bfloat16(r);
        o[j] = *reinterpret_cast<unsigned short*>(&h);
    }
    *reinterpret_cast<ushort8*>(wq + i) = o;
}

__global__ void cast_x_k(const float* __restrict__ x,
                         __hip_bfloat16* __restrict__ xb) {
    size_t i = ((size_t)blockIdx.x * 256 + threadIdx.x) * 8;
    f32x4 a = *reinterpret_cast<const f32x4*>(x + i);
    f32x4 b = *reinterpret_cast<const f32x4*>(x + i + 4);
    float v[8] = {a.x, a.y, a.z, a.w, b.x, b.y, b.z, b.w};
    ushort8 o;
#pragma unroll
    for (int j = 0; j < 8; ++j) {
        __hip_bfloat16 h = __float2bfloat16(v[j]);
        o[j] = *reinterpret_cast<unsigned short*>(&h);
    }
    *reinterpret_cast<ushort8*>(xb + i) = o;
}

// ---------------------------------------------------------------------------
// 256x256 8-phase GEMM, r3 quadrant decomposition (quad <-> staging-half
// aligned) + register persistence (24 ds_read/tile, p4 pure-MFMA) + hoisted
// issue (all 20 of a tile's reads issue at p1; drains hide under MFMA via
// compiler-counted lgkmcnt). vmcnt ledger: VM4 at ends of p1/p4/p5/p8,
// each forcing exactly the 2-load stage issued >=4 phases earlier.
// 3-bit row-XOR LDS swizzle (conflict-free, round-4 verified).
#define BUF1 65536

__global__ __launch_bounds__(512, 2) void gemm8_k(
    const __hip_bfloat16* __restrict__ A,   // [M][K]
    const __hip_bfloat16* __restrict__ B,   // [N][K]
    float* __restrict__ C,                  // [M][N]
    const float* __restrict__ sc, int M, int N, int K) {
    extern __shared__ char smem[];

    int nwg = gridDim.x, wg = blockIdx.x, swz = wg;
    if ((nwg & 7) == 0) { int cpx = nwg >> 3; swz = (wg & 7) * cpx + (wg >> 3); }
    int nbn = N >> 8;
    int brow = (swz / nbn) << 8, bcol = (swz % nbn) << 8;

    int tid = threadIdx.x, lane = tid & 63, wave = tid >> 6;
    int wm2 = wave >> 2, wn4 = wave & 3;          // 2x4 wave grid in quadrant
    int l15 = lane & 15, l16 = lane >> 4;
    int swl = (l15 & 7) << 4;                     // 3-bit row-XOR swizzle

    // regions per buffer: A = [256 rows][128B] @0, B same @32768.
    // quadrant qm/qn maps exactly to staging half (r3 alignment).
    int aoffq0 = (wm2 * 64 + l15) * 128 + ((l16 * 16) ^ swl);
    int aoffq1 = aoffq0 + 16384;                  // A-half1 (+128 rows)
    int boffq0 = 32768 + (wn4 * 32 + l15) * 128 + ((l16 * 16) ^ swl);
    int boffq1 = boffq0 + 16384;                  // B-half1

    // staging: dest byte d = tid*16 (linear); source logical = d ^ ((row&7)<<4)
    int sw_t = ((tid >> 3) & 7) << 4;
    int base_e = (tid * 16) ^ sw_t;
    int r0 = base_e >> 7;                         // 0..63
    int c0 = (base_e & 127) >> 1;                 // element col 0..63
    const __hip_bfloat16* sA = A + (size_t)(brow + r0) * K + c0;
    const __hip_bfloat16* sB = B + (size_t)(bcol + r0) * K + c0;
    size_t r64 = (size_t)64 * K, r128 = (size_t)128 * K;
    char* dA = smem + tid * 16;
    char* dB = smem + 32768 + tid * 16;

#define STG_A(BUF, H, KT) do { \
    const __hip_bfloat16* _s = sA + (size_t)(H) * r128 + (KT); \
    char* _d = dA + (BUF) + (H) * 16384; \
    gload16(_s, _d); gload16(_s + r64, _d + 8192); } while (0)
#define STG_B(BUF, H, KT) do { \
    const __hip_bfloat16* _s = sB + (size_t)(H) * r128 + (KT); \
    char* _d = dB + (BUF) + (H) * 16384; \
    gload16(_s, _d); gload16(_s + r64, _d + 8192); } while (0)

    f32x4 acc[4][8];   // [qm*2+qn][m2*2+n2]
#pragma unroll
    for (int q = 0; q < 4; ++q)
#pragma unroll
        for (int f = 0; f < 8; ++f) acc[q][f] = (f32x4)(0.f);

    short8 aqA[4][2];   // A quad qm=0 frags (persist p1..p4)
    short8 aqB[4][2];   // A quad qm=1 frags
    short8 bq0[2][2];   // B quad qn=0 frags
    short8 bq1[2][2];   // B quad qn=1 frags

#define LDQ_A(BUF, AOFF, DST) do { \
    _Pragma("unroll") for (int m2 = 0; m2 < 4; ++m2) { \
        int _o = (AOFF) + m2 * 2048; \
        DST[m2][0] = *(const short8*)(smem + (BUF) + _o); \
        DST[m2][1] = *(const short8*)(smem + (BUF) + (_o ^ 64)); } } while (0)
#define LDQ_B(BUF, BOFF, DST) do { \
    _Pragma("unroll") for (int n2 = 0; n2 < 2; ++n2) { \
        int _o = (BOFF) + n2 * 2048; \
        DST[n2][0] = *(const short8*)(smem + (BUF) + _o); \
        DST[n2][1] = *(const short8*)(smem + (BUF) + (_o ^ 64)); } } while (0)
#define MM(Q, AQ, BQ) do { \
    __builtin_amdgcn_s_setprio(1); \
    _Pragma("unroll") for (int m2 = 0; m2 < 4; ++m2) \
    _Pragma("unroll") for (int n2 = 0; n2 < 2; ++n2) { \
        acc[Q][m2*2+n2] = __builtin_amdgcn_mfma_f32_16x16x32_bf16( \
            AQ[m2][0], BQ[n2][0], acc[Q][m2*2+n2], 0, 0, 0); \
        acc[Q][m2*2+n2] = __builtin_amdgcn_mfma_f32_16x16x32_bf16( \
            AQ[m2][1], BQ[n2][1], acc[Q][m2*2+n2], 0, 0, 0); } \
    __builtin_amdgcn_s_setprio(0); } while (0)
#define BAR __builtin_amdgcn_s_barrier()
#define VM4 asm volatile("s_waitcnt vmcnt(4)" ::: "memory")
#define VM2 asm volatile("s_waitcnt vmcnt(2)" ::: "memory")
#define VM0 asm volatile("s_waitcnt vmcnt(0)" ::: "memory")

    // prologue (age order = steady-state slots s4..s8):
    // b0.B1, b0.A0, b0.A1, b0.B0 (tile0), b1.B1 (tile1)
    STG_B(0, 1, 0); STG_A(0, 0, 0); STG_A(0, 1, 0); STG_B(0, 0, 0);
    STG_B(BUF1, 1, 64);
    VM4; BAR;   // forces B1,A0,A1 of tile0; leaves b0.B0 + b1.B1 in flight

    int nit = K / 128 - 1;  // full iterations; last one peeled
    for (int it = 0; it < nit; ++it) {
        int kb1 = it * 128 + 64;    // tile 2it+1 -> b1
        int kb0 = it * 128 + 128;   // tile 2it+2 -> b0
        int kb1n = it * 128 + 192;  // tile 2it+3 -> b1
        // p1: quad(0,1); issue ALL b0 reads (aqA,bq1 + hoisted aqB)
        LDQ_A(0, aoffq0, aqA); LDQ_B(0, boffq1, bq1); LDQ_A(0, aoffq1, aqB);
        STG_A(BUF1, 0, kb1);
        BAR; MM(1, aqA, bq1); VM4; BAR;    // forces b0.B0 (s7 prev)
        // p2: quad(1,1); hoisted bq0 issue
        LDQ_B(0, boffq0, bq0);
        STG_A(BUF1, 1, kb1);
        BAR; MM(3, aqB, bq1); BAR;
        // p3: quad(1,0)
        STG_B(BUF1, 0, kb1);
        BAR; MM(2, aqB, bq0); BAR;
        // p4: quad(0,0) -- pure MFMA (aqA,bq0 persisted)
        STG_B(0, 1, kb0);
        BAR; MM(0, aqA, bq0); VM4; BAR;    // forces b1.B1, b1.A0, b1.A1
        // p5: quad(0,1) of b1
        LDQ_A(BUF1, aoffq0, aqA); LDQ_B(BUF1, boffq1, bq1); LDQ_A(BUF1, aoffq1, aqB);
        STG_A(0, 0, kb0);
        BAR; MM(1, aqA, bq1); VM4; BAR;    // forces b1.B0 (s3)
        // p6: quad(1,1)
        LDQ_B(BUF1, boffq0, bq0);
        STG_A(0, 1, kb0);
        BAR; MM(3, aqB, bq1); BAR;
        // p7: quad(1,0)
        STG_B(0, 0, kb0);
        BAR; MM(2, aqB, bq0); BAR;
        // p8: quad(0,0)
        STG_B(BUF1, 1, kb1n);
        BAR; MM(0, aqA, bq0); VM4; BAR;    // forces b0'.B1, b0'.A0, b0'.A1
    }
    // peeled last iteration: stage only b1's A0,A1,B0 (tile 2*nit+1)
    {
        int kb1 = nit * 128 + 64;
        LDQ_A(0, aoffq0, aqA); LDQ_B(0, boffq1, bq1); LDQ_A(0, aoffq1, aqB);
        STG_A(BUF1, 0, kb1);
        BAR; MM(1, aqA, bq1); VM4; BAR;    // forces b0.B0
        LDQ_B(0, boffq0, bq0);
        STG_A(BUF1, 1, kb1);
        BAR; MM(3, aqB, bq1); BAR;
        STG_B(BUF1, 0, kb1);
        BAR; MM(2, aqB, bq0); BAR;
        BAR; MM(0, aqA, bq0); VM2; BAR;    // forces b1.B1, b1.A0, b1.A1
        LDQ_A(BUF1, aoffq0, aqA); LDQ_B(BUF1, boffq1, bq1); LDQ_A(BUF1, aoffq1, aqB);
        BAR; MM(1, aqA, bq1); VM0; BAR;    // forces b1.B0
        LDQ_B(BUF1, boffq0, bq0);
        BAR; MM(3, aqB, bq1); BAR;
        BAR; MM(2, aqB, bq0); BAR;
        BAR; MM(0, aqA, bq0);
    }

    float scale = sc[0];
#pragma unroll
    for (int qm = 0; qm < 2; ++qm)
#pragma unroll
        for (int qn = 0; qn < 2; ++qn)
#pragma unroll
            for (int m2 = 0; m2 < 4; ++m2)
#pragma unroll
                for (int n2 = 0; n2 < 2; ++n2)
#pragma unroll
                    for (int r = 0; r < 4; ++r) {
                        int grow = brow + qm * 128 + wm2 * 64 + m2 * 16 + l16 * 4 + r;
                        int gcol = bcol + qn * 128 + wn4 * 32 + n2 * 16 + l15;
                        C[(size_t)grow * N + gcol] =
                            acc[qm * 2 + qn][m2 * 2 + n2][r] * scale;
                    }
}

// ---------------------------------------------------------------------------
__global__ void gemm_fallback_k(const float* __restrict__ X,
                                const float* __restrict__ W,
                                float* __restrict__ C,
                                const float* __restrict__ sc,
                                int M, int N, int K) {
    __shared__ float Xs[32][33];
    __shared__ float Ws[32][33];
    float speps = sc[1];
    int nbn = N / 32;
    int brow = (blockIdx.x / nbn) * 32;
    int bcol = (blockIdx.x % nbn) * 32;
    int tx = threadIdx.x & 31;
    int ty4 = threadIdx.x >> 5;
    float acc[4] = {0.f, 0.f, 0.f, 0.f};
    for (int kt = 0; kt < K; kt += 32) {
#pragma unroll
        for (int i = 0; i < 4; ++i) {
            int idx = threadIdx.x + i * 256;
            int r = idx >> 5, c = idx & 31;
            Xs[r][c] = X[(size_t)(brow + r) * K + kt + c];
            float wv = W[(size_t)(bcol + r) * K + kt + c];
            float t = wv / speps;
            t = fminf(fmaxf(t, -1.f), 1.f);
            Ws[r][c] = rintf(t);
        }
        __syncthreads();
#pragma unroll
        for (int kk = 0; kk < 32; ++kk) {
            float wv = Ws[tx][kk];
#pragma unroll
            for (int i = 0; i < 4; ++i) acc[i] += Xs[ty4 * 4 + i][kk] * wv;
        }
        __syncthreads();
    }
    float scale = sc[0];
#pragma unroll
    for (int i = 0; i < 4; ++i)
        C[(size_t)(brow + ty4 * 4 + i) * N + (bcol + tx)] = acc[i] * scale;
}

// ---------------------------------------------------------------------------
extern "C" void kernel_launch(void* const* d_in, const int* in_sizes, int n_in,
                              void* d_out, int out_size, void* d_ws,
                              size_t ws_size, hipStream_t stream) {
    const float* x = (const float*)d_in[0];   // [B,S,K] f32
    const float* w = (const float*)d_in[1];   // [N,K]   f32
    float* out = (float*)d_out;               // [B,S,N] f32

    const int K = 4096;
    const int N = 4096;
    int xn = in_sizes[0];                     // M*K
    int wn = in_sizes[1];                     // N*K
    int M = xn / K;

    const int NPART = 2048;
    size_t off_sc = (size_t)NPART * 8;
    size_t off_xb = off_sc + 64;
    size_t need = off_xb + ((size_t)xn + (size_t)wn) * 2;

    bool shape_ok = (M % 256 == 0) && (N % 256 == 0) && (K % 256 == 0);

    if (ws_size >= need && shape_ok) {
        double* partials = (double*)d_ws;
        float* sc = (float*)((char*)d_ws + off_sc);
        __hip_bfloat16* xb = (__hip_bfloat16*)((char*)d_ws + off_xb);
        __hip_bfloat16* wq = xb + xn;

        absmean_partial_k<<<NPART, 256, 0, stream>>>(w, partials);
        absmean_final_k<<<1, 256, 0, stream>>>(partials, sc, NPART, wn);
        quantize_w_k<<<wn / 2048, 256, 0, stream>>>(w, wq, sc);
        cast_x_k<<<xn / 2048, 256, 0, stream>>>(x, xb);

        hipFuncSetAttribute(reinterpret_cast<const void*>(gemm8_k),
                            hipFuncAttributeMaxDynamicSharedMemorySize, 131072);
        dim3 grid((M / 256) * (N / 256));
        gemm8_k<<<grid, 512, 131072, stream>>>(xb, wq, out, sc, M, N, K);
    } else {
        double* partials = (double*)d_out;
        float* sc = (float*)d_ws;
        absmean_partial_k<<<NPART, 256, 0, stream>>>(w, partials);
        absmean_final_k<<<1, 256, 0, stream>>>(partials, sc, NPART, wn);
        dim3 grid((M / 32) * (N / 32));
        gemm_fallback_k<<<grid, 256, 0, stream>>>(x, w, out, sc, M, N, K);
    }
}

// Round 7
// 194.600 us; speedup vs baseline: 1.8415x; 1.8415x over previous
//
#include <hip/hip_runtime.h>
#include <hip/hip_bf16.h>
#include <stdint.h>
#include <stddef.h>

typedef __attribute__((ext_vector_type(8))) short short8;
typedef __attribute__((ext_vector_type(4))) float f32x4;
typedef __attribute__((ext_vector_type(8))) unsigned short ushort8;

// global -> LDS direct copy, 16B per lane. LDS dest must be base + lane*16.
__device__ __forceinline__ void gload16(const void* g, void* l) {
    __builtin_amdgcn_global_load_lds(
        (__attribute__((address_space(1))) void*)g,
        (__attribute__((address_space(3))) void*)l,
        16, 0, 0);
}

// ---------------------------------------------------------------------------
__global__ void absmean_partial_k(const float* __restrict__ w,
                                  double* __restrict__ partials) {
    int tid = threadIdx.x;
    size_t base = (size_t)blockIdx.x * 8192 + (size_t)tid * 4;
    float s = 0.f;
#pragma unroll
    for (int i = 0; i < 8; ++i) {
        f32x4 v = *reinterpret_cast<const f32x4*>(w + base + (size_t)i * 1024);
        s += __builtin_fabsf(v.x) + __builtin_fabsf(v.y) +
             __builtin_fabsf(v.z) + __builtin_fabsf(v.w);
    }
    double d = (double)s;
#pragma unroll
    for (int off = 32; off > 0; off >>= 1) d += __shfl_down(d, off, 64);
    __shared__ double red[4];
    int lane = tid & 63, wid = tid >> 6;
    if (lane == 0) red[wid] = d;
    __syncthreads();
    if (tid == 0) partials[blockIdx.x] = red[0] + red[1] + red[2] + red[3];
}

__global__ void absmean_final_k(const double* __restrict__ partials,
                                float* __restrict__ sc, int nparts, int count) {
    int tid = threadIdx.x;
    double d = 0.0;
    for (int i = tid; i < nparts; i += 256) d += partials[i];
#pragma unroll
    for (int off = 32; off > 0; off >>= 1) d += __shfl_down(d, off, 64);
    __shared__ double red[4];
    int lane = tid & 63, wid = tid >> 6;
    if (lane == 0) red[wid] = d;
    __syncthreads();
    if (tid == 0) {
        double total = red[0] + red[1] + red[2] + red[3];
        float scale = (float)(total / (double)count);
        sc[0] = scale;
        sc[1] = scale + 1e-8f;
    }
}

__global__ void quantize_w_k(const float* __restrict__ w,
                             __hip_bfloat16* __restrict__ wq,
                             const float* __restrict__ sc) {
    float speps = sc[1];
    size_t i = ((size_t)blockIdx.x * 256 + threadIdx.x) * 8;
    f32x4 a = *reinterpret_cast<const f32x4*>(w + i);
    f32x4 b = *reinterpret_cast<const f32x4*>(w + i + 4);
    float v[8] = {a.x, a.y, a.z, a.w, b.x, b.y, b.z, b.w};
    ushort8 o;
#pragma unroll
    for (int j = 0; j < 8; ++j) {
        float t = v[j] / speps;
        t = fminf(fmaxf(t, -1.f), 1.f);
        float r = rintf(t);
        __hip_bfloat16 h = __float2bfloat16(r);
        o[j] = *reinterpret_cast<unsigned short*>(&h);
    }
    *reinterpret_cast<ushort8*>(wq + i) = o;
}

__global__ void cast_x_k(const float* __restrict__ x,
                         __hip_bfloat16* __restrict__ xb) {
    size_t i = ((size_t)blockIdx.x * 256 + threadIdx.x) * 8;
    f32x4 a = *reinterpret_cast<const f32x4*>(x + i);
    f32x4 b = *reinterpret_cast<const f32x4*>(x + i + 4);
    float v[8] = {a.x, a.y, a.z, a.w, b.x, b.y, b.z, b.w};
    ushort8 o;
#pragma unroll
    for (int j = 0; j < 8; ++j) {
        __hip_bfloat16 h = __float2bfloat16(v[j]);
        o[j] = *reinterpret_cast<unsigned short*>(&h);
    }
    *reinterpret_cast<ushort8*>(xb + i) = o;
}

// ---------------------------------------------------------------------------
// 256x256 8-phase GEMM. Block-quadrant decomposition with quad order
// (0,0),(0,1),(1,1),(1,0): p1 reads A0(8)+B0(4), p2 reads B1(4), p3 reads
// A1(8, overwrites aq), p4 is PURE MFMA (aq=A1 + persisted bq0). Only 64
// operand VGPRs (aq+bq0+bq1) -- r6's dual-A spill (WRITE_SIZE 5x) fixed.
// A0/B0 regions retire at p1 -> burst staging: all 4 next-tile halves issue
// at p1 (b1) / p5 (b0'), issue->force slack 3-4 phases. Only 4 counted
// waits/iter: VM8@p1, VM4@p4, VM8@p5, VM4@p8 (never below 4 in flight).
// 3-bit row-XOR LDS swizzle (conflict-free, round-4 verified).
#define BUF1 65536

__global__ __launch_bounds__(512, 2) void gemm8_k(
    const __hip_bfloat16* __restrict__ A,   // [M][K]
    const __hip_bfloat16* __restrict__ B,   // [N][K]
    float* __restrict__ C,                  // [M][N]
    const float* __restrict__ sc, int M, int N, int K) {
    extern __shared__ char smem[];

    int nwg = gridDim.x, wg = blockIdx.x, swz = wg;
    if ((nwg & 7) == 0) { int cpx = nwg >> 3; swz = (wg & 7) * cpx + (wg >> 3); }
    int nbn = N >> 8;
    int brow = (swz / nbn) << 8, bcol = (swz % nbn) << 8;

    int tid = threadIdx.x, lane = tid & 63, wave = tid >> 6;
    int wm2 = wave >> 2, wn4 = wave & 3;          // 2x4 wave grid in quadrant
    int l15 = lane & 15, l16 = lane >> 4;
    int swl = (l15 & 7) << 4;                     // 3-bit row-XOR swizzle

    // regions per buffer: A = [256 rows][128B] @0, B same @32768.
    // quadrant qm/qn maps exactly to staging half (r3 alignment).
    int aoffq0 = (wm2 * 64 + l15) * 128 + ((l16 * 16) ^ swl);
    int aoffq1 = aoffq0 + 16384;                  // A-half1 (+128 rows)
    int boffq0 = 32768 + (wn4 * 32 + l15) * 128 + ((l16 * 16) ^ swl);
    int boffq1 = boffq0 + 16384;                  // B-half1

    // staging: dest byte d = tid*16 (linear); source logical = d ^ ((row&7)<<4)
    int sw_t = ((tid >> 3) & 7) << 4;
    int base_e = (tid * 16) ^ sw_t;
    int r0 = base_e >> 7;                         // 0..63
    int c0 = (base_e & 127) >> 1;                 // element col 0..63
    const __hip_bfloat16* sA = A + (size_t)(brow + r0) * K + c0;
    const __hip_bfloat16* sB = B + (size_t)(bcol + r0) * K + c0;
    size_t r64 = (size_t)64 * K, r128 = (size_t)128 * K;
    char* dA = smem + tid * 16;
    char* dB = smem + 32768 + tid * 16;

#define STG_A(BUF, H, KT) do { \
    const __hip_bfloat16* _s = sA + (size_t)(H) * r128 + (KT); \
    char* _d = dA + (BUF) + (H) * 16384; \
    gload16(_s, _d); gload16(_s + r64, _d + 8192); } while (0)
#define STG_B(BUF, H, KT) do { \
    const __hip_bfloat16* _s = sB + (size_t)(H) * r128 + (KT); \
    char* _d = dB + (BUF) + (H) * 16384; \
    gload16(_s, _d); gload16(_s + r64, _d + 8192); } while (0)
// issue order A0,B0,B1,A1: vmcnt forcing order must match first-read order
#define STG_TILE(BUF, KT) do { \
    STG_A(BUF, 0, KT); STG_B(BUF, 0, KT); \
    STG_B(BUF, 1, KT); STG_A(BUF, 1, KT); } while (0)

    f32x4 acc[4][8];   // [qm*2+qn][m2*2+n2]
#pragma unroll
    for (int q = 0; q < 4; ++q)
#pragma unroll
        for (int f = 0; f < 8; ++f) acc[q][f] = (f32x4)(0.f);

    short8 aq[4][2];    // current A-half frags (A0 in p1-p2, A1 in p3-p4)
    short8 bq0[2][2];   // B-half0 frags -- persist p1..p4
    short8 bq1[2][2];   // B-half1 frags -- live p2..p3

#define LDQ_A(BUF, AOFF) do { \
    _Pragma("unroll") for (int m2 = 0; m2 < 4; ++m2) { \
        int _o = (AOFF) + m2 * 2048; \
        aq[m2][0] = *(const short8*)(smem + (BUF) + _o); \
        aq[m2][1] = *(const short8*)(smem + (BUF) + (_o ^ 64)); } } while (0)
#define LDQ_B(BUF, BOFF, DST) do { \
    _Pragma("unroll") for (int n2 = 0; n2 < 2; ++n2) { \
        int _o = (BOFF) + n2 * 2048; \
        DST[n2][0] = *(const short8*)(smem + (BUF) + _o); \
        DST[n2][1] = *(const short8*)(smem + (BUF) + (_o ^ 64)); } } while (0)
#define MM(Q, BQ) do { \
    __builtin_amdgcn_s_setprio(1); \
    _Pragma("unroll") for (int m2 = 0; m2 < 4; ++m2) \
    _Pragma("unroll") for (int n2 = 0; n2 < 2; ++n2) { \
        acc[Q][m2*2+n2] = __builtin_amdgcn_mfma_f32_16x16x32_bf16( \
            aq[m2][0], BQ[n2][0], acc[Q][m2*2+n2], 0, 0, 0); \
        acc[Q][m2*2+n2] = __builtin_amdgcn_mfma_f32_16x16x32_bf16( \
            aq[m2][1], BQ[n2][1], acc[Q][m2*2+n2], 0, 0, 0); } \
    __builtin_amdgcn_s_setprio(0); } while (0)
#define BAR __builtin_amdgcn_s_barrier()
#define LGKM asm volatile("s_waitcnt lgkmcnt(0)" ::: "memory")
#define VM8 asm volatile("s_waitcnt vmcnt(8)" ::: "memory")
#define VM4 asm volatile("s_waitcnt vmcnt(4)" ::: "memory")
#define VM2 asm volatile("s_waitcnt vmcnt(2)" ::: "memory")
#define VM0 asm volatile("s_waitcnt vmcnt(0)" ::: "memory")

    // prologue: tile0 -> b0 (A0,B0,B1,A1). VM4 forces A0,B0; B1,A1 in flight
    // -- identical to the steady-state p1 entry condition.
    STG_TILE(0, 0);
    VM4; BAR;

    int nit = K / 128 - 1;  // full iterations; last one peeled
    for (int it = 0; it < nit; ++it) {
        int kb1 = it * 128 + 64;    // tile 2it+1 -> b1 (read p5..p7 this iter)
        int kb0 = it * 128 + 128;   // tile 2it+2 -> b0 (read next iter p1..p3)
        // p1: quad(0,0): aq=A0(8), bq0=B0(4); burst-stage all of b1
        LDQ_A(0, aoffq0); LDQ_B(0, boffq0, bq0);
        STG_TILE(BUF1, kb1);
        BAR; LGKM; MM(0, bq0); VM8; BAR;   // forces b0.B1, b0.A1
        // p2: quad(0,1): bq1=B1(4)
        LDQ_B(0, boffq1, bq1);
        BAR; LGKM; MM(1, bq1); BAR;
        // p3: quad(1,1): aq=A1(8)
        LDQ_A(0, aoffq1);
        BAR; LGKM; MM(3, bq1); BAR;
        // p4: quad(1,0): pure MFMA (aq=A1, bq0 persisted)
        BAR; MM(2, bq0); VM4; BAR;         // forces b1.A0, b1.B0
        // p5: quad(0,0) of b1; burst-stage all of b0'
        LDQ_A(BUF1, aoffq0); LDQ_B(BUF1, boffq0, bq0);
        STG_TILE(0, kb0);
        BAR; LGKM; MM(0, bq0); VM8; BAR;   // forces b1.B1, b1.A1
        // p6: quad(0,1)
        LDQ_B(BUF1, boffq1, bq1);
        BAR; LGKM; MM(1, bq1); BAR;
        // p7: quad(1,1)
        LDQ_A(BUF1, aoffq1);
        BAR; LGKM; MM(3, bq1); BAR;
        // p8: quad(1,0): pure MFMA
        BAR; MM(2, bq0); VM4; BAR;         // forces b0'.A0, b0'.B0
    }
    // peeled last iteration (tiles 2*nit, 2*nit+1): stage only b1 at p1
    {
        int kb1 = nit * 128 + 64;
        LDQ_A(0, aoffq0); LDQ_B(0, boffq0, bq0);
        STG_TILE(BUF1, kb1);
        BAR; LGKM; MM(0, bq0); VM8; BAR;   // forces b0.B1, b0.A1
        LDQ_B(0, boffq1, bq1);
        BAR; LGKM; MM(1, bq1); BAR;
        LDQ_A(0, aoffq1);
        BAR; LGKM; MM(3, bq1); BAR;
        BAR; MM(2, bq0); VM4; BAR;         // forces b1.A0, b1.B0
        LDQ_A(BUF1, aoffq0); LDQ_B(BUF1, boffq0, bq0);
        BAR; LGKM; MM(0, bq0); VM2; BAR;   // forces b1.B1
        LDQ_B(BUF1, boffq1, bq1);
        BAR; LGKM; MM(1, bq1); VM0; BAR;   // forces b1.A1
        LDQ_A(BUF1, aoffq1);
        BAR; LGKM; MM(3, bq1); BAR;
        BAR; MM(2, bq0);
    }

    float scale = sc[0];
#pragma unroll
    for (int qm = 0; qm < 2; ++qm)
#pragma unroll
        for (int qn = 0; qn < 2; ++qn)
#pragma unroll
            for (int m2 = 0; m2 < 4; ++m2)
#pragma unroll
                for (int n2 = 0; n2 < 2; ++n2)
#pragma unroll
                    for (int r = 0; r < 4; ++r) {
                        int grow = brow + qm * 128 + wm2 * 64 + m2 * 16 + l16 * 4 + r;
                        int gcol = bcol + qn * 128 + wn4 * 32 + n2 * 16 + l15;
                        C[(size_t)grow * N + gcol] =
                            acc[qm * 2 + qn][m2 * 2 + n2][r] * scale;
                    }
}

// ---------------------------------------------------------------------------
__global__ void gemm_fallback_k(const float* __restrict__ X,
                                const float* __restrict__ W,
                                float* __restrict__ C,
                                const float* __restrict__ sc,
                                int M, int N, int K) {
    __shared__ float Xs[32][33];
    __shared__ float Ws[32][33];
    float speps = sc[1];
    int nbn = N / 32;
    int brow = (blockIdx.x / nbn) * 32;
    int bcol = (blockIdx.x % nbn) * 32;
    int tx = threadIdx.x & 31;
    int ty4 = threadIdx.x >> 5;
    float acc[4] = {0.f, 0.f, 0.f, 0.f};
    for (int kt = 0; kt < K; kt += 32) {
#pragma unroll
        for (int i = 0; i < 4; ++i) {
            int idx = threadIdx.x + i * 256;
            int r = idx >> 5, c = idx & 31;
            Xs[r][c] = X[(size_t)(brow + r) * K + kt + c];
            float wv = W[(size_t)(bcol + r) * K + kt + c];
            float t = wv / speps;
            t = fminf(fmaxf(t, -1.f), 1.f);
            Ws[r][c] = rintf(t);
        }
        __syncthreads();
#pragma unroll
        for (int kk = 0; kk < 32; ++kk) {
            float wv = Ws[tx][kk];
#pragma unroll
            for (int i = 0; i < 4; ++i) acc[i] += Xs[ty4 * 4 + i][kk] * wv;
        }
        __syncthreads();
    }
    float scale = sc[0];
#pragma unroll
    for (int i = 0; i < 4; ++i)
        C[(size_t)(brow + ty4 * 4 + i) * N + (bcol + tx)] = acc[i] * scale;
}

// ---------------------------------------------------------------------------
extern "C" void kernel_launch(void* const* d_in, const int* in_sizes, int n_in,
                              void* d_out, int out_size, void* d_ws,
                              size_t ws_size, hipStream_t stream) {
    const float* x = (const float*)d_in[0];   // [B,S,K] f32
    const float* w = (const float*)d_in[1];   // [N,K]   f32
    float* out = (float*)d_out;               // [B,S,N] f32

    const int K = 4096;
    const int N = 4096;
    int xn = in_sizes[0];                     // M*K
    int wn = in_sizes[1];                     // N*K
    int M = xn / K;

    const int NPART = 2048;
    size_t off_sc = (size_t)NPART * 8;
    size_t off_xb = off_sc + 64;
    size_t need = off_xb + ((size_t)xn + (size_t)wn) * 2;

    bool shape_ok = (M % 256 == 0) && (N % 256 == 0) && (K % 256 == 0);

    if (ws_size >= need && shape_ok) {
        double* partials = (double*)d_ws;
        float* sc = (float*)((char*)d_ws + off_sc);
        __hip_bfloat16* xb = (__hip_bfloat16*)((char*)d_ws + off_xb);
        __hip_bfloat16* wq = xb + xn;

        absmean_partial_k<<<NPART, 256, 0, stream>>>(w, partials);
        absmean_final_k<<<1, 256, 0, stream>>>(partials, sc, NPART, wn);
        quantize_w_k<<<wn / 2048, 256, 0, stream>>>(w, wq, sc);
        cast_x_k<<<xn / 2048, 256, 0, stream>>>(x, xb);

        hipFuncSetAttribute(reinterpret_cast<const void*>(gemm8_k),
                            hipFuncAttributeMaxDynamicSharedMemorySize, 131072);
        dim3 grid((M / 256) * (N / 256));
        gemm8_k<<<grid, 512, 131072, stream>>>(xb, wq, out, sc, M, N, K);
    } else {
        double* partials = (double*)d_out;
        float* sc = (float*)d_ws;
        absmean_partial_k<<<NPART, 256, 0, stream>>>(w, partials);
        absmean_final_k<<<1, 256, 0, stream>>>(partials, sc, NPART, wn);
        dim3 grid((M / 32) * (N / 32));
        gemm_fallback_k<<<grid, 256, 0, stream>>>(x, w, out, sc, M, N, K);
    }
}

// Round 8
// 163.462 us; speedup vs baseline: 2.1922x; 1.1905x over previous
//
#include <hip/hip_runtime.h>
#include <hip/hip_bf16.h>
#include <stdint.h>
#include <stddef.h>

typedef __attribute__((ext_vector_type(8))) short short8;
typedef __attribute__((ext_vector_type(4))) float f32x4;
typedef __attribute__((ext_vector_type(8))) unsigned short ushort8;

// global -> LDS direct copy, 16B per lane. LDS dest must be base + lane*16.
__device__ __forceinline__ void gload16(const void* g, void* l) {
    __builtin_amdgcn_global_load_lds(
        (__attribute__((address_space(1))) void*)g,
        (__attribute__((address_space(3))) void*)l,
        16, 0, 0);
}

// ---------------------------------------------------------------------------
__global__ void absmean_partial_k(const float* __restrict__ w,
                                  double* __restrict__ partials) {
    int tid = threadIdx.x;
    size_t base = (size_t)blockIdx.x * 8192 + (size_t)tid * 4;
    float s = 0.f;
#pragma unroll
    for (int i = 0; i < 8; ++i) {
        f32x4 v = *reinterpret_cast<const f32x4*>(w + base + (size_t)i * 1024);
        s += __builtin_fabsf(v.x) + __builtin_fabsf(v.y) +
             __builtin_fabsf(v.z) + __builtin_fabsf(v.w);
    }
    double d = (double)s;
#pragma unroll
    for (int off = 32; off > 0; off >>= 1) d += __shfl_down(d, off, 64);
    __shared__ double red[4];
    int lane = tid & 63, wid = tid >> 6;
    if (lane == 0) red[wid] = d;
    __syncthreads();
    if (tid == 0) partials[blockIdx.x] = red[0] + red[1] + red[2] + red[3];
}

__global__ void absmean_final_k(const double* __restrict__ partials,
                                float* __restrict__ sc, int nparts, int count) {
    int tid = threadIdx.x;
    double d = 0.0;
    for (int i = tid; i < nparts; i += 256) d += partials[i];
#pragma unroll
    for (int off = 32; off > 0; off >>= 1) d += __shfl_down(d, off, 64);
    __shared__ double red[4];
    int lane = tid & 63, wid = tid >> 6;
    if (lane == 0) red[wid] = d;
    __syncthreads();
    if (tid == 0) {
        double total = red[0] + red[1] + red[2] + red[3];
        float scale = (float)(total / (double)count);
        sc[0] = scale;
        sc[1] = scale + 1e-8f;
    }
}

__global__ void quantize_w_k(const float* __restrict__ w,
                             __hip_bfloat16* __restrict__ wq,
                             const float* __restrict__ sc) {
    float speps = sc[1];
    size_t i = ((size_t)blockIdx.x * 256 + threadIdx.x) * 8;
    f32x4 a = *reinterpret_cast<const f32x4*>(w + i);
    f32x4 b = *reinterpret_cast<const f32x4*>(w + i + 4);
    float v[8] = {a.x, a.y, a.z, a.w, b.x, b.y, b.z, b.w};
    ushort8 o;
#pragma unroll
    for (int j = 0; j < 8; ++j) {
        float t = v[j] / speps;
        t = fminf(fmaxf(t, -1.f), 1.f);
        float r = rintf(t);
        __hip_bfloat16 h = __float2bfloat16(r);
        o[j] = *reinterpret_cast<unsigned short*>(&h);
    }
    *reinterpret_cast<ushort8*>(wq + i) = o;
}

__global__ void cast_x_k(const float* __restrict__ x,
                         __hip_bfloat16* __restrict__ xb) {
    size_t i = ((size_t)blockIdx.x * 256 + threadIdx.x) * 8;
    f32x4 a = *reinterpret_cast<const f32x4*>(x + i);
    f32x4 b = *reinterpret_cast<const f32x4*>(x + i + 4);
    float v[8] = {a.x, a.y, a.z, a.w, b.x, b.y, b.z, b.w};
    ushort8 o;
#pragma unroll
    for (int j = 0; j < 8; ++j) {
        __hip_bfloat16 h = __float2bfloat16(v[j]);
        o[j] = *reinterpret_cast<unsigned short*>(&h);
    }
    *reinterpret_cast<ushort8*>(xb + i) = o;
}

// ---------------------------------------------------------------------------
// 256x256 8-phase GEMM. r4's spread-staging ledger + quad order
// (0,0),(0,1),(1,1),(1,0): p1 reads A0(8)+B0(4), p2 reads B1(4), p3 reads
// A1(8), p4 pure MFMA. 24 ds_read_b128/K-tile (floor), 64 operand VGPRs.
// Staging: ONE half-tile (2 gloads) per phase in first-read order
// (p1:A0', p2:B0', p3:B1', p4:A1' -> other buffer). Wait ledger (simulated
// steady-state + prologue + epilogue): VM4 at ends of p1,p2,p4,p5,p6,p8;
// invariant "4 loads in flight entering p1". 3-bit row-XOR swizzle
// (conflict-free, r4-verified).
#define BUF1 65536

__global__ __launch_bounds__(512, 2) void gemm8_k(
    const __hip_bfloat16* __restrict__ A,   // [M][K]
    const __hip_bfloat16* __restrict__ B,   // [N][K]
    float* __restrict__ C,                  // [M][N]
    const float* __restrict__ sc, int M, int N, int K) {
    extern __shared__ char smem[];

    int nwg = gridDim.x, wg = blockIdx.x, swz = wg;
    if ((nwg & 7) == 0) { int cpx = nwg >> 3; swz = (wg & 7) * cpx + (wg >> 3); }
    int nbn = N >> 8;
    int brow = (swz / nbn) << 8, bcol = (swz % nbn) << 8;

    int tid = threadIdx.x, lane = tid & 63, wave = tid >> 6;
    int wm2 = wave >> 2, wn4 = wave & 3;          // 2x4 wave grid in quadrant
    int l15 = lane & 15, l16 = lane >> 4;
    int swl = (l15 & 7) << 4;                     // 3-bit row-XOR swizzle

    // regions per buffer: A = [256 rows][128B] @0, B same @32768.
    // quadrant qm/qn maps exactly to staging half (row-halves).
    int aoffq0 = (wm2 * 64 + l15) * 128 + ((l16 * 16) ^ swl);
    int aoffq1 = aoffq0 + 16384;                  // A-half1 (+128 rows)
    int boffq0 = 32768 + (wn4 * 32 + l15) * 128 + ((l16 * 16) ^ swl);
    int boffq1 = boffq0 + 16384;                  // B-half1

    // staging: dest byte d = tid*16 (linear); source logical = d ^ ((row&7)<<4)
    int sw_t = ((tid >> 3) & 7) << 4;
    int base_e = (tid * 16) ^ sw_t;
    int r0 = base_e >> 7;                         // 0..63
    int c0 = (base_e & 127) >> 1;                 // element col 0..63
    const __hip_bfloat16* sA = A + (size_t)(brow + r0) * K + c0;
    const __hip_bfloat16* sB = B + (size_t)(bcol + r0) * K + c0;
    size_t r64 = (size_t)64 * K, r128 = (size_t)128 * K;
    char* dA = smem + tid * 16;
    char* dB = smem + 32768 + tid * 16;

#define STG_A(BUF, H, KT) do { \
    const __hip_bfloat16* _s = sA + (size_t)(H) * r128 + (KT); \
    char* _d = dA + (BUF) + (H) * 16384; \
    gload16(_s, _d); gload16(_s + r64, _d + 8192); } while (0)
#define STG_B(BUF, H, KT) do { \
    const __hip_bfloat16* _s = sB + (size_t)(H) * r128 + (KT); \
    char* _d = dB + (BUF) + (H) * 16384; \
    gload16(_s, _d); gload16(_s + r64, _d + 8192); } while (0)

    f32x4 acc[4][8];   // [qm*2+qn][m2*2+n2]
#pragma unroll
    for (int q = 0; q < 4; ++q)
#pragma unroll
        for (int f = 0; f < 8; ++f) acc[q][f] = (f32x4)(0.f);

    short8 aq[4][2];    // current A-half frags (A0 in p1-p2, A1 in p3-p4)
    short8 bq0[2][2];   // B-half0 frags -- persist p1..p4
    short8 bq1[2][2];   // B-half1 frags -- live p2..p3

#define LDQ_A(BUF, AOFF) do { \
    _Pragma("unroll") for (int m2 = 0; m2 < 4; ++m2) { \
        int _o = (AOFF) + m2 * 2048; \
        aq[m2][0] = *(const short8*)(smem + (BUF) + _o); \
        aq[m2][1] = *(const short8*)(smem + (BUF) + (_o ^ 64)); } } while (0)
#define LDQ_B(BUF, BOFF, DST) do { \
    _Pragma("unroll") for (int n2 = 0; n2 < 2; ++n2) { \
        int _o = (BOFF) + n2 * 2048; \
        DST[n2][0] = *(const short8*)(smem + (BUF) + _o); \
        DST[n2][1] = *(const short8*)(smem + (BUF) + (_o ^ 64)); } } while (0)
#define MM(Q, BQ) do { \
    __builtin_amdgcn_s_setprio(1); \
    _Pragma("unroll") for (int m2 = 0; m2 < 4; ++m2) \
    _Pragma("unroll") for (int n2 = 0; n2 < 2; ++n2) { \
        acc[Q][m2*2+n2] = __builtin_amdgcn_mfma_f32_16x16x32_bf16( \
            aq[m2][0], BQ[n2][0], acc[Q][m2*2+n2], 0, 0, 0); \
        acc[Q][m2*2+n2] = __builtin_amdgcn_mfma_f32_16x16x32_bf16( \
            aq[m2][1], BQ[n2][1], acc[Q][m2*2+n2], 0, 0, 0); } \
    __builtin_amdgcn_s_setprio(0); } while (0)
#define BAR __builtin_amdgcn_s_barrier()
#define LGKM asm volatile("s_waitcnt lgkmcnt(0)" ::: "memory")
#define VM4 asm volatile("s_waitcnt vmcnt(4)" ::: "memory")
#define VM2 asm volatile("s_waitcnt vmcnt(2)" ::: "memory")
#define VM0 asm volatile("s_waitcnt vmcnt(0)" ::: "memory")

    // prologue: tile0 -> b0, issue order A0,B0,B1,A1. VM4 forces A0,B0;
    // leaves {B1,A1} = 4 in flight = steady-state p1 entry invariant.
    STG_A(0, 0, 0); STG_B(0, 0, 0); STG_B(0, 1, 0); STG_A(0, 1, 0);
    VM4; BAR;

    int nit = K / 128 - 1;  // full iterations; last one peeled
    for (int it = 0; it < nit; ++it) {
        int kb1 = it * 128 + 64;    // tile 2it+1 -> b1 (read p5..p7)
        int kb0 = it * 128 + 128;   // tile 2it+2 -> b0 (read next iter)
        // p1: quad(0,0): aq=A0, bq0=B0 | stage b1.A0
        LDQ_A(0, aoffq0); LDQ_B(0, boffq0, bq0);
        STG_A(BUF1, 0, kb1);
        BAR; LGKM; MM(0, bq0); VM4; BAR;   // forces b0.B1 (for p2)
        // p2: quad(0,1): bq1=B1 | stage b1.B0
        LDQ_B(0, boffq1, bq1);
        STG_B(BUF1, 0, kb1);
        BAR; LGKM; MM(1, bq1); VM4; BAR;   // forces b0.A1 (for p3)
        // p3: quad(1,1): aq=A1 | stage b1.B1
        LDQ_A(0, aoffq1);
        STG_B(BUF1, 1, kb1);
        BAR; LGKM; MM(3, bq1); BAR;
        // p4: quad(1,0): pure MFMA | stage b1.A1
        STG_A(BUF1, 1, kb1);
        BAR; MM(2, bq0); VM4; BAR;         // forces b1.A0, b1.B0 (for p5)
        // p5: quad(0,0) of b1 | stage b0'.A0
        LDQ_A(BUF1, aoffq0); LDQ_B(BUF1, boffq0, bq0);
        STG_A(0, 0, kb0);
        BAR; LGKM; MM(0, bq0); VM4; BAR;   // forces b1.B1 (for p6)
        // p6: quad(0,1) | stage b0'.B0
        LDQ_B(BUF1, boffq1, bq1);
        STG_B(0, 0, kb0);
        BAR; LGKM; MM(1, bq1); VM4; BAR;   // forces b1.A1 (for p7)
        // p7: quad(1,1) | stage b0'.B1
        LDQ_A(BUF1, aoffq1);
        STG_B(0, 1, kb0);
        BAR; LGKM; MM(3, bq1); BAR;
        // p8: quad(1,0): pure MFMA | stage b0'.A1
        STG_A(0, 1, kb0);
        BAR; MM(2, bq0); VM4; BAR;         // forces b0'.A0, b0'.B0 (for p1')
    }
    // peeled last iteration (tiles 2*nit, 2*nit+1): stage b1 at p1-p4 only
    {
        int kb1 = nit * 128 + 64;
        LDQ_A(0, aoffq0); LDQ_B(0, boffq0, bq0);
        STG_A(BUF1, 0, kb1);
        BAR; LGKM; MM(0, bq0); VM4; BAR;   // forces b0.B1
        LDQ_B(0, boffq1, bq1);
        STG_B(BUF1, 0, kb1);
        BAR; LGKM; MM(1, bq1); VM4; BAR;   // forces b0.A1
        LDQ_A(0, aoffq1);
        STG_B(BUF1, 1, kb1);
        BAR; LGKM; MM(3, bq1); BAR;
        STG_A(BUF1, 1, kb1);
        BAR; MM(2, bq0); VM4; BAR;         // forces b1.A0, b1.B0
        LDQ_A(BUF1, aoffq0); LDQ_B(BUF1, boffq0, bq0);
        BAR; LGKM; MM(0, bq0); VM2; BAR;   // forces b1.B1
        LDQ_B(BUF1, boffq1, bq1);
        BAR; LGKM; MM(1, bq1); VM0; BAR;   // forces b1.A1
        LDQ_A(BUF1, aoffq1);
        BAR; LGKM; MM(3, bq1); BAR;
        BAR; MM(2, bq0);
    }

    float scale = sc[0];
#pragma unroll
    for (int qm = 0; qm < 2; ++qm)
#pragma unroll
        for (int qn = 0; qn < 2; ++qn)
#pragma unroll
            for (int m2 = 0; m2 < 4; ++m2)
#pragma unroll
                for (int n2 = 0; n2 < 2; ++n2)
#pragma unroll
                    for (int r = 0; r < 4; ++r) {
                        int grow = brow + qm * 128 + wm2 * 64 + m2 * 16 + l16 * 4 + r;
                        int gcol = bcol + qn * 128 + wn4 * 32 + n2 * 16 + l15;
                        C[(size_t)grow * N + gcol] =
                            acc[qm * 2 + qn][m2 * 2 + n2][r] * scale;
                    }
}

// ---------------------------------------------------------------------------
__global__ void gemm_fallback_k(const float* __restrict__ X,
                                const float* __restrict__ W,
                                float* __restrict__ C,
                                const float* __restrict__ sc,
                                int M, int N, int K) {
    __shared__ float Xs[32][33];
    __shared__ float Ws[32][33];
    float speps = sc[1];
    int nbn = N / 32;
    int brow = (blockIdx.x / nbn) * 32;
    int bcol = (blockIdx.x % nbn) * 32;
    int tx = threadIdx.x & 31;
    int ty4 = threadIdx.x >> 5;
    float acc[4] = {0.f, 0.f, 0.f, 0.f};
    for (int kt = 0; kt < K; kt += 32) {
#pragma unroll
        for (int i = 0; i < 4; ++i) {
            int idx = threadIdx.x + i * 256;
            int r = idx >> 5, c = idx & 31;
            Xs[r][c] = X[(size_t)(brow + r) * K + kt + c];
            float wv = W[(size_t)(bcol + r) * K + kt + c];
            float t = wv / speps;
            t = fminf(fmaxf(t, -1.f), 1.f);
            Ws[r][c] = rintf(t);
        }
        __syncthreads();
#pragma unroll
        for (int kk = 0; kk < 32; ++kk) {
            float wv = Ws[tx][kk];
#pragma unroll
            for (int i = 0; i < 4; ++i) acc[i] += Xs[ty4 * 4 + i][kk] * wv;
        }
        __syncthreads();
    }
    float scale = sc[0];
#pragma unroll
    for (int i = 0; i < 4; ++i)
        C[(size_t)(brow + ty4 * 4 + i) * N + (bcol + tx)] = acc[i] * scale;
}

// ---------------------------------------------------------------------------
extern "C" void kernel_launch(void* const* d_in, const int* in_sizes, int n_in,
                              void* d_out, int out_size, void* d_ws,
                              size_t ws_size, hipStream_t stream) {
    const float* x = (const float*)d_in[0];   // [B,S,K] f32
    const float* w = (const float*)d_in[1];   // [N,K]   f32
    float* out = (float*)d_out;               // [B,S,N] f32

    const int K = 4096;
    const int N = 4096;
    int xn = in_sizes[0];                     // M*K
    int wn = in_sizes[1];                     // N*K
    int M = xn / K;

    const int NPART = 2048;
    size_t off_sc = (size_t)NPART * 8;
    size_t off_xb = off_sc + 64;
    size_t need = off_xb + ((size_t)xn + (size_t)wn) * 2;

    bool shape_ok = (M % 256 == 0) && (N % 256 == 0) && (K % 256 == 0);

    if (ws_size >= need && shape_ok) {
        double* partials = (double*)d_ws;
        float* sc = (float*)((char*)d_ws + off_sc);
        __hip_bfloat16* xb = (__hip_bfloat16*)((char*)d_ws + off_xb);
        __hip_bfloat16* wq = xb + xn;

        absmean_partial_k<<<NPART, 256, 0, stream>>>(w, partials);
        absmean_final_k<<<1, 256, 0, stream>>>(partials, sc, NPART, wn);
        quantize_w_k<<<wn / 2048, 256, 0, stream>>>(w, wq, sc);
        cast_x_k<<<xn / 2048, 256, 0, stream>>>(x, xb);

        hipFuncSetAttribute(reinterpret_cast<const void*>(gemm8_k),
                            hipFuncAttributeMaxDynamicSharedMemorySize, 131072);
        dim3 grid((M / 256) * (N / 256));
        gemm8_k<<<grid, 512, 131072, stream>>>(xb, wq, out, sc, M, N, K);
    } else {
        double* partials = (double*)d_out;
        float* sc = (float*)d_ws;
        absmean_partial_k<<<NPART, 256, 0, stream>>>(w, partials);
        absmean_final_k<<<1, 256, 0, stream>>>(partials, sc, NPART, wn);
        dim3 grid((M / 32) * (N / 32));
        gemm_fallback_k<<<grid, 256, 0, stream>>>(x, w, out, sc, M, N, K);
    }
}